// Round 15
// baseline (316.555 us; speedup 1.0000x reference)
//
#include <hip/hip_runtime.h>

// DiT block, B=4 N=512 D=1024 H=16 HD=64 HID=4096 RP_HID=64. All f32 I/O.
// R20 (resubmit x4; R12/R13 GPUAcquisitionTimeout, R14 container-failed —
//      kernel re-audited: LDS 17664B exact, Bs idx<4416, biasbuf offsets
//      in-bounds, uniform barriers; failure is infra, not this diff):
//      bias path amortization. R19 counters: k_pre 45us, HBM 28%, VALU 40%,
//      MFMA 1.7%, conflicts 0, occ 40% -> latency-bound on BLOCK STARTUP
//      (4096 tiny blocks x ~12 dependent weight loads each, ~22 serial
//      blocks/CU). Fix: 4 tiles per bias block (both mh x 2 n), weights
//      preloaded once, double-buffered Bs so tile t's global write overlaps
//      tile t+1's compute. Bias grid 4096->1024; k_pre 5632->2560 (3:2
//      convert:bias interleave). Keep: hand-rolled RNE f2b (R18: HIP cast
//      regressed +5.6us), Bs stride 276 (conflicts 0), XCD swizzle (neutral).
//      History: R12 355->329; R16 merge; R17 reg-direct bias ->313.5;
//      R13/R15 tile null; R18 cast regression (reverted); R19 312.4.
// ws (byte off): mod@0(128K) | xn@128K(4M) | xm@+4M(8M) | wqkvb@+12M(6M) |
//   wprojb@+18M(2M) | wfc1b@+20M(8M) | wfc2b@+28M(8M) | qkvb@+36M(12M) |
//   biasb@+48M(32M) | hb@+80M(16M) | parts/projb@+96M(16M)

#define B_ 4
#define N_ 512
#define D_ 1024
#define H_ 16
#define HID_ 4096
#define M_ (B_*N_)

typedef unsigned short u16;
typedef __attribute__((ext_vector_type(8))) short bf16x8;
typedef __attribute__((ext_vector_type(4))) float f32x4;

__device__ __forceinline__ float b2f(u16 u){
  union { unsigned int i; float f; } x; x.i = ((unsigned int)u) << 16; return x.f;
}
__device__ __forceinline__ u16 f2b(float f){          // RNE, 3-op bit math
  unsigned int u = __float_as_uint(f);
  return (u16)((u + 0x7fffu + ((u >> 16) & 1u)) >> 16);
}

__device__ __forceinline__ void gload16(const u16* __restrict__ g, u16* l){
#if defined(__has_builtin) && __has_builtin(__builtin_amdgcn_global_load_lds)
  __builtin_amdgcn_global_load_lds(
      (const __attribute__((address_space(1))) unsigned int*)g,
      (__attribute__((address_space(3))) unsigned int*)l, 16, 0, 0);
#else
  *(uint4*)l = *(const uint4*)g;
#endif
}

// XCD-chunked bijective swizzle (requires nwg % 8 == 0)
__device__ __forceinline__ int xcd_swz(int flat, int nwg){
  return (flat & 7) * (nwg >> 3) + (flat >> 3);
}

// ---------------- merged pre-pass: converts + adaLN GEMV + rel-pos bias
// 2560 = 5*512 blocks; r=blk%5: r<3 -> convert (g*3+r of 1536),
// r>=3 -> bias block (g*2+r-3 of 1024), each bias block does 4 tiles.
__global__ __launch_bounds__(256) void k_pre(
    const float* __restrict__ w_qkv, u16* __restrict__ wqkvb,
    const float* __restrict__ w_proj, u16* __restrict__ wprojb,
    const float* __restrict__ w_fc1, u16* __restrict__ wfc1b,
    const float* __restrict__ w_fc2, u16* __restrict__ wfc2b,
    const float* __restrict__ t_emb, const float* __restrict__ w_ada,
    const float* __restrict__ b_ada, float* __restrict__ mod,
    const float* __restrict__ rel, const int* __restrict__ amask,
    const float* __restrict__ w_rp1, const float* __restrict__ b_rp1,
    const float* __restrict__ w_rp2, const float* __restrict__ b_rp2,
    u16* __restrict__ biasbuf)
{
  // union: convert st = 16384 B; bias Bs double-buffer = 2*16*276*2 = 17664 B
  __shared__ __align__(16) char smem[17664];
  int blk = blockIdx.x, tid = threadIdx.x;
  int w = tid >> 6, lane = tid & 63, ln = lane & 15, quad = lane >> 4;
  int g = blk / 5, r = blk % 5;

  if (r < 3){
    int cblk = g*3 + r;                    // 0..1535
    float* st = (float*)smem;              // silu(t_emb), 4 batches, 16KB
    #pragma unroll
    for (int i = 0; i < 16; i++){
      int idx = tid + i*256;
      float x = t_emb[idx];
      st[idx] = x / (1.f + __expf(-x));
    }

    const float* s; u16* d; size_t base;
    if      (cblk <  384){ s = w_qkv;  d = wqkvb;  base = (size_t)cblk*8192; }
    else if (cblk <  512){ s = w_proj; d = wprojb; base = (size_t)(cblk-384)*8192; }
    else if (cblk < 1024){ s = w_fc1;  d = wfc1b;  base = (size_t)(cblk-512)*8192; }
    else                 { s = w_fc2;  d = wfc2b;  base = (size_t)(cblk-1024)*8192; }
    float4 a[4], bq[4];
    #pragma unroll
    for (int it=0; it<4; it++){
      size_t i = base + (size_t)it*2048 + (size_t)tid*8;
      a[it]  = *(const float4*)(s+i);
      bq[it] = *(const float4*)(s+i+4);
    }

    int j = cblk*4 + w;
    const float* wr = w_ada + (size_t)j*D_ + 4*lane;
    float4 wv[4];
    #pragma unroll
    for (int i=0;i<4;i++) wv[i] = *(const float4*)(wr + i*256);

    #pragma unroll
    for (int it=0; it<4; it++){
      size_t i = base + (size_t)it*2048 + (size_t)tid*8;
      u16 o[8] = {f2b(a[it].x),f2b(a[it].y),f2b(a[it].z),f2b(a[it].w),
                  f2b(bq[it].x),f2b(bq[it].y),f2b(bq[it].z),f2b(bq[it].w)};
      *(uint4*)(d+i) = *(const uint4*)o;
    }

    __syncthreads();

    float acc[B_] = {};
    #pragma unroll
    for (int i=0;i<4;i++){
      int p = 4*lane + 256*i;
      #pragma unroll
      for (int b=0;b<B_;b++){
        float4 sv = *(const float4*)&st[b*D_ + p];
        acc[b] += wv[i].x*sv.x + wv[i].y*sv.y + wv[i].z*sv.z + wv[i].w*sv.w;
      }
    }
    #pragma unroll
    for (int b=0;b<B_;b++)
      #pragma unroll
      for (int o=32;o>0;o>>=1) acc[b] += __shfl_down(acc[b], o);
    if (lane == 0){
      float bj = b_ada[j];
      #pragma unroll
      for (int b=0;b<B_;b++) mod[b*6*D_ + j] = acc[b] + bj;
    }
    return;
  }

  // ---- bias path: 4 tiles per block (mh in {0,1} x 2 consecutive n)
  int bidx = g*2 + (r - 3);                // 0..1023
  int b  = bidx >> 8;                      // batch
  int np = bidx & 255;                     // n-pair index; n = np*2 + {0,1}

  // preload weights ONCE per block
  const float* w2p = w_rp2 + ln*64 + quad*8;
  float4 a0 = *(const float4*)(w2p);
  float4 a1 = *(const float4*)(w2p+4);
  float4 a2 = *(const float4*)(w2p+32);
  float4 a3 = *(const float4*)(w2p+36);
  u16 afe[16] = {f2b(a0.x),f2b(a0.y),f2b(a0.z),f2b(a0.w),
                 f2b(a1.x),f2b(a1.y),f2b(a1.z),f2b(a1.w),
                 f2b(a2.x),f2b(a2.y),f2b(a2.z),f2b(a2.w),
                 f2b(a3.x),f2b(a3.y),f2b(a3.z),f2b(a3.w)};
  bf16x8 af0 = *(const bf16x8*)&afe[0];
  bf16x8 af1 = *(const bf16x8*)&afe[8];

  float w1l[16], w1h[16], b1l[8], b1h[8];
  *(float4*)&w1l[0]  = *(const float4*)(w_rp1 + quad*16);
  *(float4*)&w1l[4]  = *(const float4*)(w_rp1 + quad*16 + 4);
  *(float4*)&w1l[8]  = *(const float4*)(w_rp1 + quad*16 + 8);
  *(float4*)&w1l[12] = *(const float4*)(w_rp1 + quad*16 + 12);
  *(float4*)&w1h[0]  = *(const float4*)(w_rp1 + 64 + quad*16);
  *(float4*)&w1h[4]  = *(const float4*)(w_rp1 + 64 + quad*16 + 4);
  *(float4*)&w1h[8]  = *(const float4*)(w_rp1 + 64 + quad*16 + 8);
  *(float4*)&w1h[12] = *(const float4*)(w_rp1 + 64 + quad*16 + 12);
  *(float4*)&b1l[0]  = *(const float4*)(b_rp1 + quad*8);
  *(float4*)&b1l[4]  = *(const float4*)(b_rp1 + quad*8 + 4);
  *(float4*)&b1h[0]  = *(const float4*)(b_rp1 + 32 + quad*8);
  *(float4*)&b1h[4]  = *(const float4*)(b_rp1 + 32 + quad*8 + 4);
  float b2v[4];
  #pragma unroll
  for (int i=0;i<4;i++) b2v[i] = b_rp2[quad*4 + i];

  #pragma unroll
  for (int tt=0; tt<4; tt++){
    int mh = tt & 1;
    int n  = np*2 + (tt >> 1);
    u16* Bs = (u16*)smem + (tt & 1)*4416;  // double buffer, 16*276 u16 each

    #pragma unroll
    for (int t=0; t<4; t++){
      int mt = w*4 + t;
      int m = mh*256 + mt*16 + ln;
      float2 r01 = *(const float2*)(rel + ((size_t)((b*N_ + n)*N_) + m)*2);
      bool valid = amask[b*N_ + m] != 0;
      u16 hv[16];
      #pragma unroll
      for (int j2=0;j2<8;j2++){
        float hl = w1l[2*j2]*r01.x + w1l[2*j2+1]*r01.y + b1l[j2];
        hv[j2]   = f2b(hl > 0.f ? hl : 0.f);
        float hh = w1h[2*j2]*r01.x + w1h[2*j2+1]*r01.y + b1h[j2];
        hv[8+j2] = f2b(hh > 0.f ? hh : 0.f);
      }
      bf16x8 bf0 = *(const bf16x8*)&hv[0];
      bf16x8 bf1 = *(const bf16x8*)&hv[8];
      f32x4 c = {};
      c = __builtin_amdgcn_mfma_f32_16x16x32_bf16(af0, bf0, c, 0,0,0);
      c = __builtin_amdgcn_mfma_f32_16x16x32_bf16(af1, bf1, c, 0,0,0);
      #pragma unroll
      for (int i=0;i<4;i++){
        int h = quad*4 + i;
        float val = valid ? (c[i] + b2v[i]) : -1e30f;
        Bs[h*276 + mt*16 + ln] = f2b(val);
      }
    }
    __syncthreads();

    #pragma unroll
    for (int it=0; it<8; it++){
      int idx2 = it*256 + tid;
      int rr = idx2 >> 7, cc = idx2 & 127;
      size_t rb = (((size_t)(b*H_ + rr)*N_) + n)*N_ + mh*256;
      ((unsigned int*)(biasbuf + rb))[cc] = ((const unsigned int*)(Bs + rr*276))[cc];
    }
    // next tile uses the other Bs buffer; its compute is fenced from this
    // tile's LDS reads by the per-tile __syncthreads above (reads complete
    // before the wave issues the next tile's barrier).
  }
}

// ---------------- LayerNorm + adaLN modulate -> bf16 (LN1)
__global__ __launch_bounds__(256) void k_lnmod(const float* __restrict__ xin,
    const float* __restrict__ g, const float* __restrict__ be,
    const float* __restrict__ mod, int shift_idx, int scale_idx,
    u16* __restrict__ xn)
{
  int row = blockIdx.x;
  int b = row >> 9;
  float v[4]; float s = 0.f, s2 = 0.f;
  #pragma unroll
  for (int i=0;i<4;i++){
    float x = xin[(size_t)row*D_ + threadIdx.x + i*256];
    v[i] = x; s += x; s2 += x*x;
  }
  #pragma unroll
  for (int o=32;o>0;o>>=1){ s += __shfl_down(s,o); s2 += __shfl_down(s2,o); }
  __shared__ float rs[4], rs2[4];
  int w = threadIdx.x >> 6;
  if ((threadIdx.x & 63)==0){ rs[w]=s; rs2[w]=s2; }
  __syncthreads();
  s = rs[0]+rs[1]+rs[2]+rs[3]; s2 = rs2[0]+rs2[1]+rs2[2]+rs2[3];
  float mu = s * (1.f/D_);
  float var = s2 * (1.f/D_) - mu*mu;
  float rstd = rsqrtf(var + 1e-5f);
  const float* mrow = mod + b*6*D_;
  #pragma unroll
  for (int i=0;i<4;i++){
    int d = threadIdx.x + i*256;
    float xg = (v[i]-mu)*rstd*g[d] + be[d];
    xn[(size_t)row*D_ + d] = f2b(xg * (1.f + mrow[scale_idx*D_ + d]) + mrow[shift_idx*D_ + d]);
  }
}

// ---------------- 64x128-tile MFMA GEMM, BK=64, XOR-swizzle, direct epilogue.
enum { EPI_PLAIN=0, EPI_GELU=1 };

template<int EPI>
__global__ __launch_bounds__(256) void k_gemm64(const u16* __restrict__ A,
    const u16* __restrict__ W, const float* __restrict__ Wb, int K, int ldc,
    u16* __restrict__ o_u16)
{
  __shared__ __align__(16) u16 Al[64*64];
  __shared__ __align__(16) u16 Wl[128*64];
  int nwg = gridDim.x * gridDim.y;
  int flat = xcd_swz(blockIdx.y * gridDim.x + blockIdx.x, nwg);
  int bx = flat % gridDim.x, by = flat / gridDim.x;
  int row0 = by*64, col0 = bx*128;
  int tid = threadIdx.x;
  int w = tid >> 6, lane = tid & 63, ln = lane & 15, quad = lane >> 4;
  int wy = w >> 1, wx = w & 1;
  int srow = tid >> 3;
  int schunk = (tid & 7) ^ (srow & 7);
  const u16* Ag = A + (size_t)(row0 + srow)*K + schunk*8;
  const u16* Wg = W + (size_t)(col0 + srow)*K + schunk*8;
  int aoff[2][2], woff[4][2];
  #pragma unroll
  for (int ms=0; ms<2; ms++){
    int r = 32*wy + 16*ms + ln;
    #pragma unroll
    for (int kk=0; kk<2; kk++)
      aoff[ms][kk] = r*64 + (((kk*4+quad) ^ (ln&7))*8);
  }
  #pragma unroll
  for (int ns=0; ns<4; ns++){
    int r = 64*wx + 16*ns + ln;
    #pragma unroll
    for (int kk=0; kk<2; kk++)
      woff[ns][kk] = r*64 + (((kk*4+quad) ^ (ln&7))*8);
  }
  f32x4 acc[2][4] = {};
  for (int k0 = 0; k0 < K; k0 += 64){
    gload16(Ag + k0,                  Al + tid*8);
    gload16(Ag + k0 + (size_t)32*K,   Al + 2048 + tid*8);
    #pragma unroll
    for (int i=0;i<4;i++)
      gload16(Wg + k0 + (size_t)(32*i)*K, Wl + i*2048 + tid*8);
    __syncthreads();
    #pragma unroll
    for (int kk=0; kk<2; kk++){
      bf16x8 af[2], bfr[4];
      #pragma unroll
      for (int ms=0; ms<2; ms++) af[ms]  = *(const bf16x8*)&Al[aoff[ms][kk]];
      #pragma unroll
      for (int ns=0; ns<4; ns++) bfr[ns] = *(const bf16x8*)&Wl[woff[ns][kk]];
      #pragma unroll
      for (int ms=0; ms<2; ms++)
        #pragma unroll
        for (int ns=0; ns<4; ns++)
          acc[ms][ns] = __builtin_amdgcn_mfma_f32_16x16x32_bf16(af[ms], bfr[ns], acc[ms][ns], 0,0,0);
    }
    __syncthreads();
  }
  #pragma unroll
  for (int ms=0; ms<2; ms++){
    #pragma unroll
    for (int ns=0; ns<4; ns++){
      int c = col0 + 64*wx + 16*ns + ln;
      float wb = Wb[c];
      #pragma unroll
      for (int i=0;i<4;i++){
        int r = row0 + 32*wy + 16*ms + quad*4 + i;
        float val = acc[ms][ns][i] + wb;
        if (EPI == EPI_GELU) val = 0.5f*val*(1.f + erff(val*0.70710678f));
        o_u16[(size_t)r*ldc + c] = f2b(val);
      }
    }
  }
}

// ---------------- 128x128-tile split-K GEMM -> bf16 partials (4 slices)
__global__ __launch_bounds__(256) void k_gemm(const u16* __restrict__ A,
    const u16* __restrict__ W, int K, int Kslice, int ldc,
    u16* __restrict__ part)
{
  __shared__ __align__(16) u16 Al[128*64];
  __shared__ __align__(16) u16 Wl[128*64];
  int nwg = gridDim.x * gridDim.y;
  int flat = xcd_swz(blockIdx.y * gridDim.x + blockIdx.x, nwg);
  int bx = flat % gridDim.x, by = flat / gridDim.x;
  int row0 = by*128, col0 = bx*128;
  int tid = threadIdx.x;
  int w = tid >> 6, lane = tid & 63, ln = lane & 15, quad = lane >> 4;
  int wy = w >> 1, wx = w & 1;
  int srow = tid >> 3;
  int schunk = (tid & 7) ^ (srow & 7);
  const u16* Ag = A + (size_t)(row0 + srow)*K + schunk*8;
  const u16* Wg = W + (size_t)(col0 + srow)*K + schunk*8;
  int aoff[4][2], woff[4][2];
  #pragma unroll
  for (int ms=0; ms<4; ms++){
    int r = 64*wy + 16*ms + ln;
    #pragma unroll
    for (int kk=0; kk<2; kk++)
      aoff[ms][kk] = r*64 + (((kk*4+quad) ^ (ln&7))*8);
  }
  #pragma unroll
  for (int ns=0; ns<4; ns++){
    int r = 64*wx + 16*ns + ln;
    #pragma unroll
    for (int kk=0; kk<2; kk++)
      woff[ns][kk] = r*64 + (((kk*4+quad) ^ (ln&7))*8);
  }
  f32x4 acc[4][4] = {};
  int kbeg = blockIdx.z * Kslice;
  for (int k0 = kbeg; k0 < kbeg + Kslice; k0 += 64){
    #pragma unroll
    for (int i=0;i<4;i++){
      gload16(Ag + k0 + (size_t)(32*i)*K, Al + i*2048 + tid*8);
      gload16(Wg + k0 + (size_t)(32*i)*K, Wl + i*2048 + tid*8);
    }
    __syncthreads();
    #pragma unroll
    for (int kk=0; kk<2; kk++){
      bf16x8 af[4], bfr[4];
      #pragma unroll
      for (int ms=0; ms<4; ms++) af[ms]  = *(const bf16x8*)&Al[aoff[ms][kk]];
      #pragma unroll
      for (int ns=0; ns<4; ns++) bfr[ns] = *(const bf16x8*)&Wl[woff[ns][kk]];
      #pragma unroll
      for (int ms=0; ms<4; ms++)
        #pragma unroll
        for (int ns=0; ns<4; ns++)
          acc[ms][ns] = __builtin_amdgcn_mfma_f32_16x16x32_bf16(af[ms], bfr[ns], acc[ms][ns], 0,0,0);
    }
    __syncthreads();
  }
  u16* pbase = part + (size_t)blockIdx.z*M_*ldc;
  #pragma unroll
  for (int ms=0; ms<4; ms++){
    #pragma unroll
    for (int ns=0; ns<4; ns++){
      int c = col0 + 64*wx + 16*ns + ln;
      #pragma unroll
      for (int i=0;i<4;i++){
        int r = row0 + 64*wy + 16*ms + quad*4 + i;
        pbase[(size_t)r*ldc + c] = f2b(acc[ms][ns][i]);
      }
    }
  }
}

// ---------------- 4-slice reduce + bias + gate + residual -> f32 out
template<int GIDX>
__global__ __launch_bounds__(256) void k_red4(const u16* __restrict__ part,
    const float* __restrict__ Wb, const float* __restrict__ mod,
    const float* __restrict__ resid, float* __restrict__ outp)
{
  size_t i = ((size_t)blockIdx.x*256 + threadIdx.x)*4;
  int c = (int)(i & 1023); int r = (int)(i >> 10); int b = r >> 9;
  uint2 a0 = *(const uint2*)(part + i);
  uint2 a1 = *(const uint2*)(part + (size_t)M_*D_ + i);
  uint2 a2 = *(const uint2*)(part + (size_t)2*M_*D_ + i);
  uint2 a3 = *(const uint2*)(part + (size_t)3*M_*D_ + i);
  float4 pv;
  pv.x = b2f((u16)(a0.x&0xffff)) + b2f((u16)(a1.x&0xffff)) + b2f((u16)(a2.x&0xffff)) + b2f((u16)(a3.x&0xffff));
  pv.y = b2f((u16)(a0.x>>16))    + b2f((u16)(a1.x>>16))    + b2f((u16)(a2.x>>16))    + b2f((u16)(a3.x>>16));
  pv.z = b2f((u16)(a0.y&0xffff)) + b2f((u16)(a1.y&0xffff)) + b2f((u16)(a2.y&0xffff)) + b2f((u16)(a3.y&0xffff));
  pv.w = b2f((u16)(a0.y>>16))    + b2f((u16)(a1.y>>16))    + b2f((u16)(a2.y>>16))    + b2f((u16)(a3.y>>16));
  float4 x4 = *(const float4*)(resid + i);
  float4 bi = *(const float4*)(Wb + c);
  float4 g4 = *(const float4*)(mod + b*6*D_ + GIDX*D_ + c);
  float4 o;
  o.x = x4.x + g4.x*(pv.x + bi.x);
  o.y = x4.y + g4.y*(pv.y + bi.y);
  o.z = x4.z + g4.z*(pv.z + bi.z);
  o.w = x4.w + g4.w*(pv.w + bi.w);
  *(float4*)(outp + i) = o;
}

// ---------------- PROJ (bias already in GEMM epilogue) + gate_s + residual
// -> xm, LN2+mod -> xn.
__global__ __launch_bounds__(256) void k_redln(const u16* __restrict__ proj,
    const float* __restrict__ mod, const float* __restrict__ resid,
    const float* __restrict__ g, const float* __restrict__ be,
    float* __restrict__ xm, u16* __restrict__ xn)
{
  int row = blockIdx.x, b = row >> 9, tid = threadIdx.x;
  size_t i = (size_t)row*D_ + tid*4;
  int c = tid*4;
  uint2 a0 = *(const uint2*)(proj + i);
  float4 pv;
  pv.x = b2f((u16)(a0.x&0xffff));
  pv.y = b2f((u16)(a0.x>>16));
  pv.z = b2f((u16)(a0.y&0xffff));
  pv.w = b2f((u16)(a0.y>>16));
  float4 x4 = *(const float4*)(resid + i);
  float4 g4 = *(const float4*)(mod + b*6*D_ + 2*D_ + c);
  float4 mid;
  mid.x = x4.x + g4.x*pv.x;
  mid.y = x4.y + g4.y*pv.y;
  mid.z = x4.z + g4.z*pv.z;
  mid.w = x4.w + g4.w*pv.w;
  *(float4*)(xm + i) = mid;
  float s = mid.x+mid.y+mid.z+mid.w;
  float s2 = mid.x*mid.x+mid.y*mid.y+mid.z*mid.z+mid.w*mid.w;
  #pragma unroll
  for (int o=32;o>0;o>>=1){ s += __shfl_down(s,o); s2 += __shfl_down(s2,o); }
  __shared__ float rs[4], rs2[4];
  int w = tid >> 6;
  if ((tid & 63)==0){ rs[w]=s; rs2[w]=s2; }
  __syncthreads();
  s = rs[0]+rs[1]+rs[2]+rs[3]; s2 = rs2[0]+rs2[1]+rs2[2]+rs2[3];
  float mu = s * (1.f/D_);
  float var = s2 * (1.f/D_) - mu*mu;
  float rstd = rsqrtf(var + 1e-5f);
  const float* mrow = mod + b*6*D_;
  float4 gg = *(const float4*)(g + c);
  float4 bb = *(const float4*)(be + c);
  float4 sc = *(const float4*)(mrow + 4*D_ + c);
  float4 sh = *(const float4*)(mrow + 3*D_ + c);
  u16 o[4];
  o[0] = f2b(((mid.x-mu)*rstd*gg.x + bb.x)*(1.f+sc.x) + sh.x);
  o[1] = f2b(((mid.y-mu)*rstd*gg.y + bb.y)*(1.f+sc.y) + sh.y);
  o[2] = f2b(((mid.z-mu)*rstd*gg.z + bb.z)*(1.f+sc.z) + sh.z);
  o[3] = f2b(((mid.w-mu)*rstd*gg.w + bb.w)*(1.f+sc.w) + sh.w);
  *(uint2*)(xn + i) = *(const uint2*)o;
}

// ---------------- flash attention: block = (nt64, h, b), 4 waves, 64 q-rows
__global__ __launch_bounds__(256) void k_attn(const u16* __restrict__ qkv,
    const u16* __restrict__ biasbuf, u16* __restrict__ attn_out)
{
  __shared__ __align__(16) u16 Qs[64*72];
  __shared__ __align__(16) u16 Ks[64*72];
  __shared__ __align__(16) u16 Vt[64*72];
  __shared__ __align__(16) u16 Ps[4*16*72];
  int nt = blockIdx.x, h = blockIdx.y, b = blockIdx.z;
  int n0 = nt*64;
  int tid = threadIdx.x;
  int w = tid >> 6, lane = tid & 63, ln = lane & 15, quad = lane >> 4;

  {
    int row = tid >> 2, cb = (tid & 3)*16;
    const u16* src = qkv + (size_t)(b*N_ + n0 + row)*3072 + h*64 + cb;
    uint4 q0 = *(const uint4*)src, q1 = *(const uint4*)(src+8);
    uint4* dst = (uint4*)&Qs[row*72 + cb];
    dst[0] = q0; dst[1] = q1;
  }
  __syncthreads();
  bf16x8 qf[2];
  qf[0] = *(const bf16x8*)&Qs[(16*w+ln)*72 + quad*8];
  qf[1] = *(const bf16x8*)&Qs[(16*w+ln)*72 + 32 + quad*8];

  f32x4 oacc[4] = {};
  float rmax[4] = {-3e38f,-3e38f,-3e38f,-3e38f};
  float rsum[4] = {0.f,0.f,0.f,0.f};
  const u16* bp = biasbuf + (((size_t)(b*H_ + h)*N_) + n0 + 16*w)*N_ + ln;

  for (int mt = 0; mt < 8; mt++){
    __syncthreads();
    {
      int r = tid >> 2, cb = (tid & 3)*16;
      const u16* kp = qkv + (size_t)(b*N_ + mt*64 + r)*3072 + 1024 + h*64 + cb;
      uint4 k0 = *(const uint4*)kp, k1 = *(const uint4*)(kp+8);
      uint4* kd = (uint4*)&Ks[r*72 + cb];
      kd[0] = k0; kd[1] = k1;
      const u16* vp = qkv + (size_t)(b*N_ + mt*64 + r)*3072 + 2048 + h*64 + cb;
      uint4 v0 = *(const uint4*)vp, v1 = *(const uint4*)(vp+8);
      u16 ve[16];
      *(uint4*)&ve[0] = v0; *(uint4*)&ve[8] = v1;
      #pragma unroll
      for (int j=0;j<16;j++) Vt[(cb+j)*72 + r] = ve[j];
    }
    __syncthreads();

    u16 bl[4][4];
    #pragma unroll
    for (int cs=0; cs<4; cs++)
      #pragma unroll
      for (int i=0;i<4;i++)
        bl[cs][i] = bp[(size_t)(quad*4+i)*N_ + mt*64 + 16*cs];

    f32x4 s[4];
    #pragma unroll
    for (int cs=0; cs<4; cs++){
      bf16x8 k0f = *(const bf16x8*)&Ks[(16*cs+ln)*72 + quad*8];
      bf16x8 k1f = *(const bf16x8*)&Ks[(16*cs+ln)*72 + 32 + quad*8];
      f32x4 z = {};
      z = __builtin_amdgcn_mfma_f32_16x16x32_bf16(qf[0], k0f, z, 0,0,0);
      z = __builtin_amdgcn_mfma_f32_16x16x32_bf16(qf[1], k1f, z, 0,0,0);
      s[cs] = z;
    }
    #pragma unroll
    for (int cs=0; cs<4; cs++)
      #pragma unroll
      for (int i=0;i<4;i++)
        s[cs][i] = s[cs][i]*0.125f + b2f(bl[cs][i]);

    #pragma unroll
    for (int i=0;i<4;i++){
      float tm = fmaxf(fmaxf(s[0][i], s[1][i]), fmaxf(s[2][i], s[3][i]));
      #pragma unroll
      for (int o=1;o<16;o<<=1) tm = fmaxf(tm, __shfl_xor(tm, o));
      float nm = fmaxf(rmax[i], tm);
      float alpha = __expf(rmax[i] - nm);
      rmax[i] = nm;
      float ps = 0.f;
      #pragma unroll
      for (int cs=0; cs<4; cs++){
        float p = __expf(s[cs][i] - nm);
        s[cs][i] = p; ps += p;
      }
      #pragma unroll
      for (int o=1;o<16;o<<=1) ps += __shfl_xor(ps, o);
      rsum[i] = rsum[i]*alpha + ps;
      #pragma unroll
      for (int ds=0; ds<4; ds++) oacc[ds][i] *= alpha;
    }

    #pragma unroll
    for (int cs=0; cs<4; cs++)
      #pragma unroll
      for (int i=0;i<4;i++)
        Ps[w*1152 + (quad*4+i)*72 + 16*cs + ln] = f2b(s[cs][i]);

    bf16x8 pf0 = *(const bf16x8*)&Ps[w*1152 + ln*72 + quad*8];
    bf16x8 pf1 = *(const bf16x8*)&Ps[w*1152 + ln*72 + 32 + quad*8];
    #pragma unroll
    for (int ds=0; ds<4; ds++){
      bf16x8 v0f = *(const bf16x8*)&Vt[(16*ds+ln)*72 + quad*8];
      bf16x8 v1f = *(const bf16x8*)&Vt[(16*ds+ln)*72 + 32 + quad*8];
      oacc[ds] = __builtin_amdgcn_mfma_f32_16x16x32_bf16(pf0, v0f, oacc[ds], 0,0,0);
      oacc[ds] = __builtin_amdgcn_mfma_f32_16x16x32_bf16(pf1, v1f, oacc[ds], 0,0,0);
    }
  }

  #pragma unroll
  for (int i=0;i<4;i++){
    float inv = 1.f / rsum[i];
    int r = b*N_ + n0 + 16*w + quad*4 + i;
    #pragma unroll
    for (int ds=0; ds<4; ds++)
      attn_out[(size_t)r*D_ + h*64 + 16*ds + ln] = f2b(oacc[ds][i]*inv);
  }
}

extern "C" void kernel_launch(void* const* d_in, const int* in_sizes, int n_in,
                              void* d_out, int out_size, void* d_ws, size_t ws_size,
                              hipStream_t stream) {
  const float* x      = (const float*)d_in[0];
  const float* t_emb  = (const float*)d_in[1];
  const float* rel    = (const float*)d_in[2];
  const int*   amask  = (const int*)d_in[3];
  const float* w_ada  = (const float*)d_in[4];
  const float* b_ada  = (const float*)d_in[5];
  const float* g1     = (const float*)d_in[6];
  const float* beta1  = (const float*)d_in[7];
  const float* g2     = (const float*)d_in[8];
  const float* beta2  = (const float*)d_in[9];
  const float* w_qkv  = (const float*)d_in[10];
  const float* b_qkv  = (const float*)d_in[11];
  const float* w_proj = (const float*)d_in[12];
  const float* b_proj = (const float*)d_in[13];
  const float* w_rp1  = (const float*)d_in[14];
  const float* b_rp1  = (const float*)d_in[15];
  const float* w_rp2  = (const float*)d_in[16];
  const float* b_rp2  = (const float*)d_in[17];
  const float* w_fc1  = (const float*)d_in[18];
  const float* b_fc1  = (const float*)d_in[19];
  const float* w_fc2  = (const float*)d_in[20];
  const float* b_fc2  = (const float*)d_in[21];
  float* outp = (float*)d_out;

  const size_t MB = 1u<<20;
  char* wsb = (char*)d_ws;
  float* mod   = (float*)(wsb);
  u16*  xn     = (u16*) (wsb + 131072);
  float* xm    = (float*)(wsb + 131072 + 4*MB);
  u16*  wqkvb  = (u16*) (wsb + 131072 + 12*MB);
  u16*  wprojb = (u16*) (wsb + 131072 + 18*MB);
  u16*  wfc1b  = (u16*) (wsb + 131072 + 20*MB);
  u16*  wfc2b  = (u16*) (wsb + 131072 + 28*MB);
  u16*  qkvb   = (u16*) (wsb + 131072 + 36*MB);
  u16*  biasb  = (u16*) (wsb + 131072 + 48*MB);
  u16*  hb     = (u16*) (wsb + 131072 + 80*MB);
  u16*  parts  = (u16*) (wsb + 131072 + 96*MB);   // also projb (4.2MB)

  // 1) merged pre-pass: converts + adaLN mod + rel-pos bias (one launch)
  k_pre<<<2560, 256, 0, stream>>>(
      w_qkv, wqkvb, w_proj, wprojb, w_fc1, wfc1b, w_fc2, wfc2b,
      t_emb, w_ada, b_ada, mod,
      rel, amask, w_rp1, b_rp1, w_rp2, b_rp2, biasb);
  // 2) LN1
  k_lnmod<<<M_, 256, 0, stream>>>(x, g1, beta1, mod, 0, 1, xn);
  // 3) QKV 64x128 direct (768 blk = 3/CU balanced, XCD-swizzled)
  k_gemm64<EPI_PLAIN><<<dim3(3072/128, M_/64), 256, 0, stream>>>(
      xn, wqkvb, b_qkv, D_, 3072, qkvb);
  // 4) attention
  k_attn<<<dim3(8, H_, B_), 256, 0, stream>>>(qkvb, biasb, xn);
  // 5) PROJ 64x128 direct, bias fused (256 blk = 1/CU, XCD-swizzled)
  k_gemm64<EPI_PLAIN><<<dim3(D_/128, M_/64), 256, 0, stream>>>(
      xn, wprojb, b_proj, D_, D_, parts);
  // 6) PROJ gate+residual -> xm, LN2 -> xn
  k_redln<<<M_, 256, 0, stream>>>(parts, mod, x, g2, beta2, xm, xn);
  // 7) FC1 64x128 + GELU (1024 blk = 4/CU, XCD-swizzled)
  k_gemm64<EPI_GELU><<<dim3(HID_/128, M_/64), 256, 0, stream>>>(
      xn, wfc1b, b_fc1, D_, HID_, hb);
  // 8) FC2 split-K x4 (512 blk = 2/CU, XCD-swizzled per z)
  k_gemm<<<dim3(D_/128, M_/128, 4), 256, 0, stream>>>(
      hb, wfc2b, HID_, HID_/4, D_, parts);
  // 9) FC2 reduce -> out
  k_red4<5><<<2048, 256, 0, stream>>>(parts, b_fc2, mod, xm, outp);
}

// Round 16
// 303.895 us; speedup vs baseline: 1.0417x; 1.0417x over previous
//
#include <hip/hip_runtime.h>

// DiT block, B=4 N=512 D=1024 H=16 HD=64 HID=4096 RP_HID=64. All f32 I/O.
// R21: (a) REVERT R20 bias amortization — measured 50us/occ 23% vs R19's
//      45us/occ 40%: k_pre is latency-bound and needs MANY small blocks
//      (TLP), not fewer big ones. Back to R19's 5632-grid register-direct
//      bias path (measured 312.4 total).
//      (b) NEW: k_attn bias tile staged in LDS. Old: 16 scalar u16 global
//      loads/thread/K-tile (4x32B segments/wave-instr, 8x under-vectorized).
//      New: 64x64 bf16 tile staged with 2x uint4/thread inside the existing
//      K/V staging block (same barriers, zero new syncs), read from LDS.
//      +9KB LDS (46KB tot, >=3 blk/CU at 512-blk grid).
//      History: R12 355->329; R16 merge; R17 reg-direct bias ->313.5;
//      R13/R15 tile null; R18 cast regression (reverted); R19 312.4;
//      R20 amortization regressed (reverted).
// ws (byte off): mod@0(128K) | xn@128K(4M) | xm@+4M(8M) | wqkvb@+12M(6M) |
//   wprojb@+18M(2M) | wfc1b@+20M(8M) | wfc2b@+28M(8M) | qkvb@+36M(12M) |
//   biasb@+48M(32M) | hb@+80M(16M) | parts/projb@+96M(16M)

#define B_ 4
#define N_ 512
#define D_ 1024
#define H_ 16
#define HID_ 4096
#define M_ (B_*N_)

typedef unsigned short u16;
typedef __attribute__((ext_vector_type(8))) short bf16x8;
typedef __attribute__((ext_vector_type(4))) float f32x4;

__device__ __forceinline__ float b2f(u16 u){
  union { unsigned int i; float f; } x; x.i = ((unsigned int)u) << 16; return x.f;
}
__device__ __forceinline__ u16 f2b(float f){          // RNE, 3-op bit math
  unsigned int u = __float_as_uint(f);
  return (u16)((u + 0x7fffu + ((u >> 16) & 1u)) >> 16);
}

__device__ __forceinline__ void gload16(const u16* __restrict__ g, u16* l){
#if defined(__has_builtin) && __has_builtin(__builtin_amdgcn_global_load_lds)
  __builtin_amdgcn_global_load_lds(
      (const __attribute__((address_space(1))) unsigned int*)g,
      (__attribute__((address_space(3))) unsigned int*)l, 16, 0, 0);
#else
  *(uint4*)l = *(const uint4*)g;
#endif
}

// XCD-chunked bijective swizzle (requires nwg % 8 == 0)
__device__ __forceinline__ int xcd_swz(int flat, int nwg){
  return (flat & 7) * (nwg >> 3) + (flat >> 3);
}

// ---------------- merged pre-pass: converts + adaLN GEMV + rel-pos bias
// 5632 = 11*512 blocks; r=blk%11: r<3 -> convert (g*3+r of 1536),
// r>=3 -> bias (g*8+r-3 of 4096).
__global__ __launch_bounds__(256) void k_pre(
    const float* __restrict__ w_qkv, u16* __restrict__ wqkvb,
    const float* __restrict__ w_proj, u16* __restrict__ wprojb,
    const float* __restrict__ w_fc1, u16* __restrict__ wfc1b,
    const float* __restrict__ w_fc2, u16* __restrict__ wfc2b,
    const float* __restrict__ t_emb, const float* __restrict__ w_ada,
    const float* __restrict__ b_ada, float* __restrict__ mod,
    const float* __restrict__ rel, const int* __restrict__ amask,
    const float* __restrict__ w_rp1, const float* __restrict__ b_rp1,
    const float* __restrict__ w_rp2, const float* __restrict__ b_rp2,
    u16* __restrict__ biasbuf)
{
  __shared__ __align__(16) char smem[16384];
  int blk = blockIdx.x, tid = threadIdx.x;
  int w = tid >> 6, lane = tid & 63, ln = lane & 15, quad = lane >> 4;
  int g = blk / 11, r = blk % 11;

  if (r < 3){
    int cblk = g*3 + r;                    // 0..1535
    float* st = (float*)smem;              // silu(t_emb), 4 batches, 16KB
    #pragma unroll
    for (int i = 0; i < 16; i++){
      int idx = tid + i*256;
      float x = t_emb[idx];
      st[idx] = x / (1.f + __expf(-x));
    }

    const float* s; u16* d; size_t base;
    if      (cblk <  384){ s = w_qkv;  d = wqkvb;  base = (size_t)cblk*8192; }
    else if (cblk <  512){ s = w_proj; d = wprojb; base = (size_t)(cblk-384)*8192; }
    else if (cblk < 1024){ s = w_fc1;  d = wfc1b;  base = (size_t)(cblk-512)*8192; }
    else                 { s = w_fc2;  d = wfc2b;  base = (size_t)(cblk-1024)*8192; }
    float4 a[4], bq[4];
    #pragma unroll
    for (int it=0; it<4; it++){
      size_t i = base + (size_t)it*2048 + (size_t)tid*8;
      a[it]  = *(const float4*)(s+i);
      bq[it] = *(const float4*)(s+i+4);
    }

    int j = cblk*4 + w;
    const float* wr = w_ada + (size_t)j*D_ + 4*lane;
    float4 wv[4];
    #pragma unroll
    for (int i=0;i<4;i++) wv[i] = *(const float4*)(wr + i*256);

    #pragma unroll
    for (int it=0; it<4; it++){
      size_t i = base + (size_t)it*2048 + (size_t)tid*8;
      u16 o[8] = {f2b(a[it].x),f2b(a[it].y),f2b(a[it].z),f2b(a[it].w),
                  f2b(bq[it].x),f2b(bq[it].y),f2b(bq[it].z),f2b(bq[it].w)};
      *(uint4*)(d+i) = *(const uint4*)o;
    }

    __syncthreads();

    float acc[B_] = {};
    #pragma unroll
    for (int i=0;i<4;i++){
      int p = 4*lane + 256*i;
      #pragma unroll
      for (int b=0;b<B_;b++){
        float4 sv = *(const float4*)&st[b*D_ + p];
        acc[b] += wv[i].x*sv.x + wv[i].y*sv.y + wv[i].z*sv.z + wv[i].w*sv.w;
      }
    }
    #pragma unroll
    for (int b=0;b<B_;b++)
      #pragma unroll
      for (int o=32;o>0;o>>=1) acc[b] += __shfl_down(acc[b], o);
    if (lane == 0){
      float bj = b_ada[j];
      #pragma unroll
      for (int b=0;b<B_;b++) mod[b*6*D_ + j] = acc[b] + bj;
    }
    return;
  }

  // ---- bias path (register-direct, no Hs staging)
  int idx = g*8 + (r - 3);                 // 0..4095
  int mh = idx & 1, n = (idx >> 1) & 511, b = idx >> 10;
  u16* Bs = (u16*)smem;                    // [16][276] u16

  const float* w2p = w_rp2 + ln*64 + quad*8;
  float4 a0 = *(const float4*)(w2p);
  float4 a1 = *(const float4*)(w2p+4);
  float4 a2 = *(const float4*)(w2p+32);
  float4 a3 = *(const float4*)(w2p+36);
  u16 afe[16] = {f2b(a0.x),f2b(a0.y),f2b(a0.z),f2b(a0.w),
                 f2b(a1.x),f2b(a1.y),f2b(a1.z),f2b(a1.w),
                 f2b(a2.x),f2b(a2.y),f2b(a2.z),f2b(a2.w),
                 f2b(a3.x),f2b(a3.y),f2b(a3.z),f2b(a3.w)};
  bf16x8 af0 = *(const bf16x8*)&afe[0];
  bf16x8 af1 = *(const bf16x8*)&afe[8];

  float w1l[16], w1h[16], b1l[8], b1h[8];
  *(float4*)&w1l[0]  = *(const float4*)(w_rp1 + quad*16);
  *(float4*)&w1l[4]  = *(const float4*)(w_rp1 + quad*16 + 4);
  *(float4*)&w1l[8]  = *(const float4*)(w_rp1 + quad*16 + 8);
  *(float4*)&w1l[12] = *(const float4*)(w_rp1 + quad*16 + 12);
  *(float4*)&w1h[0]  = *(const float4*)(w_rp1 + 64 + quad*16);
  *(float4*)&w1h[4]  = *(const float4*)(w_rp1 + 64 + quad*16 + 4);
  *(float4*)&w1h[8]  = *(const float4*)(w_rp1 + 64 + quad*16 + 8);
  *(float4*)&w1h[12] = *(const float4*)(w_rp1 + 64 + quad*16 + 12);
  *(float4*)&b1l[0]  = *(const float4*)(b_rp1 + quad*8);
  *(float4*)&b1l[4]  = *(const float4*)(b_rp1 + quad*8 + 4);
  *(float4*)&b1h[0]  = *(const float4*)(b_rp1 + 32 + quad*8);
  *(float4*)&b1h[4]  = *(const float4*)(b_rp1 + 32 + quad*8 + 4);
  float b2v[4];
  #pragma unroll
  for (int i=0;i<4;i++) b2v[i] = b_rp2[quad*4 + i];

  #pragma unroll
  for (int t=0; t<4; t++){
    int mt = w*4 + t;
    int m = mh*256 + mt*16 + ln;
    float2 r01 = *(const float2*)(rel + ((size_t)((b*N_ + n)*N_) + m)*2);
    bool valid = amask[b*N_ + m] != 0;
    u16 hv[16];
    #pragma unroll
    for (int j2=0;j2<8;j2++){
      float hl = w1l[2*j2]*r01.x + w1l[2*j2+1]*r01.y + b1l[j2];
      hv[j2]   = f2b(hl > 0.f ? hl : 0.f);
      float hh = w1h[2*j2]*r01.x + w1h[2*j2+1]*r01.y + b1h[j2];
      hv[8+j2] = f2b(hh > 0.f ? hh : 0.f);
    }
    bf16x8 bf0 = *(const bf16x8*)&hv[0];
    bf16x8 bf1 = *(const bf16x8*)&hv[8];
    f32x4 c = {};
    c = __builtin_amdgcn_mfma_f32_16x16x32_bf16(af0, bf0, c, 0,0,0);
    c = __builtin_amdgcn_mfma_f32_16x16x32_bf16(af1, bf1, c, 0,0,0);
    #pragma unroll
    for (int i=0;i<4;i++){
      int h = quad*4 + i;
      float val = valid ? (c[i] + b2v[i]) : -1e30f;
      Bs[h*276 + mt*16 + ln] = f2b(val);
    }
  }
  __syncthreads();

  #pragma unroll
  for (int it=0; it<8; it++){
    int idx2 = it*256 + tid;
    int rr = idx2 >> 7, cc = idx2 & 127;
    size_t rb = (((size_t)(b*H_ + rr)*N_) + n)*N_ + mh*256;
    ((unsigned int*)(biasbuf + rb))[cc] = ((const unsigned int*)(Bs + rr*276))[cc];
  }
}

// ---------------- LayerNorm + adaLN modulate -> bf16 (LN1)
__global__ __launch_bounds__(256) void k_lnmod(const float* __restrict__ xin,
    const float* __restrict__ g, const float* __restrict__ be,
    const float* __restrict__ mod, int shift_idx, int scale_idx,
    u16* __restrict__ xn)
{
  int row = blockIdx.x;
  int b = row >> 9;
  float v[4]; float s = 0.f, s2 = 0.f;
  #pragma unroll
  for (int i=0;i<4;i++){
    float x = xin[(size_t)row*D_ + threadIdx.x + i*256];
    v[i] = x; s += x; s2 += x*x;
  }
  #pragma unroll
  for (int o=32;o>0;o>>=1){ s += __shfl_down(s,o); s2 += __shfl_down(s2,o); }
  __shared__ float rs[4], rs2[4];
  int w = threadIdx.x >> 6;
  if ((threadIdx.x & 63)==0){ rs[w]=s; rs2[w]=s2; }
  __syncthreads();
  s = rs[0]+rs[1]+rs[2]+rs[3]; s2 = rs2[0]+rs2[1]+rs2[2]+rs2[3];
  float mu = s * (1.f/D_);
  float var = s2 * (1.f/D_) - mu*mu;
  float rstd = rsqrtf(var + 1e-5f);
  const float* mrow = mod + b*6*D_;
  #pragma unroll
  for (int i=0;i<4;i++){
    int d = threadIdx.x + i*256;
    float xg = (v[i]-mu)*rstd*g[d] + be[d];
    xn[(size_t)row*D_ + d] = f2b(xg * (1.f + mrow[scale_idx*D_ + d]) + mrow[shift_idx*D_ + d]);
  }
}

// ---------------- 64x128-tile MFMA GEMM, BK=64, XOR-swizzle, direct epilogue.
enum { EPI_PLAIN=0, EPI_GELU=1 };

template<int EPI>
__global__ __launch_bounds__(256) void k_gemm64(const u16* __restrict__ A,
    const u16* __restrict__ W, const float* __restrict__ Wb, int K, int ldc,
    u16* __restrict__ o_u16)
{
  __shared__ __align__(16) u16 Al[64*64];
  __shared__ __align__(16) u16 Wl[128*64];
  int nwg = gridDim.x * gridDim.y;
  int flat = xcd_swz(blockIdx.y * gridDim.x + blockIdx.x, nwg);
  int bx = flat % gridDim.x, by = flat / gridDim.x;
  int row0 = by*64, col0 = bx*128;
  int tid = threadIdx.x;
  int w = tid >> 6, lane = tid & 63, ln = lane & 15, quad = lane >> 4;
  int wy = w >> 1, wx = w & 1;
  int srow = tid >> 3;
  int schunk = (tid & 7) ^ (srow & 7);
  const u16* Ag = A + (size_t)(row0 + srow)*K + schunk*8;
  const u16* Wg = W + (size_t)(col0 + srow)*K + schunk*8;
  int aoff[2][2], woff[4][2];
  #pragma unroll
  for (int ms=0; ms<2; ms++){
    int r = 32*wy + 16*ms + ln;
    #pragma unroll
    for (int kk=0; kk<2; kk++)
      aoff[ms][kk] = r*64 + (((kk*4+quad) ^ (ln&7))*8);
  }
  #pragma unroll
  for (int ns=0; ns<4; ns++){
    int r = 64*wx + 16*ns + ln;
    #pragma unroll
    for (int kk=0; kk<2; kk++)
      woff[ns][kk] = r*64 + (((kk*4+quad) ^ (ln&7))*8);
  }
  f32x4 acc[2][4] = {};
  for (int k0 = 0; k0 < K; k0 += 64){
    gload16(Ag + k0,                  Al + tid*8);
    gload16(Ag + k0 + (size_t)32*K,   Al + 2048 + tid*8);
    #pragma unroll
    for (int i=0;i<4;i++)
      gload16(Wg + k0 + (size_t)(32*i)*K, Wl + i*2048 + tid*8);
    __syncthreads();
    #pragma unroll
    for (int kk=0; kk<2; kk++){
      bf16x8 af[2], bfr[4];
      #pragma unroll
      for (int ms=0; ms<2; ms++) af[ms]  = *(const bf16x8*)&Al[aoff[ms][kk]];
      #pragma unroll
      for (int ns=0; ns<4; ns++) bfr[ns] = *(const bf16x8*)&Wl[woff[ns][kk]];
      #pragma unroll
      for (int ms=0; ms<2; ms++)
        #pragma unroll
        for (int ns=0; ns<4; ns++)
          acc[ms][ns] = __builtin_amdgcn_mfma_f32_16x16x32_bf16(af[ms], bfr[ns], acc[ms][ns], 0,0,0);
    }
    __syncthreads();
  }
  #pragma unroll
  for (int ms=0; ms<2; ms++){
    #pragma unroll
    for (int ns=0; ns<4; ns++){
      int c = col0 + 64*wx + 16*ns + ln;
      float wb = Wb[c];
      #pragma unroll
      for (int i=0;i<4;i++){
        int r = row0 + 32*wy + 16*ms + quad*4 + i;
        float val = acc[ms][ns][i] + wb;
        if (EPI == EPI_GELU) val = 0.5f*val*(1.f + erff(val*0.70710678f));
        o_u16[(size_t)r*ldc + c] = f2b(val);
      }
    }
  }
}

// ---------------- 128x128-tile split-K GEMM -> bf16 partials (4 slices)
__global__ __launch_bounds__(256) void k_gemm(const u16* __restrict__ A,
    const u16* __restrict__ W, int K, int Kslice, int ldc,
    u16* __restrict__ part)
{
  __shared__ __align__(16) u16 Al[128*64];
  __shared__ __align__(16) u16 Wl[128*64];
  int nwg = gridDim.x * gridDim.y;
  int flat = xcd_swz(blockIdx.y * gridDim.x + blockIdx.x, nwg);
  int bx = flat % gridDim.x, by = flat / gridDim.x;
  int row0 = by*128, col0 = bx*128;
  int tid = threadIdx.x;
  int w = tid >> 6, lane = tid & 63, ln = lane & 15, quad = lane >> 4;
  int wy = w >> 1, wx = w & 1;
  int srow = tid >> 3;
  int schunk = (tid & 7) ^ (srow & 7);
  const u16* Ag = A + (size_t)(row0 + srow)*K + schunk*8;
  const u16* Wg = W + (size_t)(col0 + srow)*K + schunk*8;
  int aoff[4][2], woff[4][2];
  #pragma unroll
  for (int ms=0; ms<4; ms++){
    int r = 64*wy + 16*ms + ln;
    #pragma unroll
    for (int kk=0; kk<2; kk++)
      aoff[ms][kk] = r*64 + (((kk*4+quad) ^ (ln&7))*8);
  }
  #pragma unroll
  for (int ns=0; ns<4; ns++){
    int r = 64*wx + 16*ns + ln;
    #pragma unroll
    for (int kk=0; kk<2; kk++)
      woff[ns][kk] = r*64 + (((kk*4+quad) ^ (ln&7))*8);
  }
  f32x4 acc[4][4] = {};
  int kbeg = blockIdx.z * Kslice;
  for (int k0 = kbeg; k0 < kbeg + Kslice; k0 += 64){
    #pragma unroll
    for (int i=0;i<4;i++){
      gload16(Ag + k0 + (size_t)(32*i)*K, Al + i*2048 + tid*8);
      gload16(Wg + k0 + (size_t)(32*i)*K, Wl + i*2048 + tid*8);
    }
    __syncthreads();
    #pragma unroll
    for (int kk=0; kk<2; kk++){
      bf16x8 af[4], bfr[4];
      #pragma unroll
      for (int ms=0; ms<4; ms++) af[ms]  = *(const bf16x8*)&Al[aoff[ms][kk]];
      #pragma unroll
      for (int ns=0; ns<4; ns++) bfr[ns] = *(const bf16x8*)&Wl[woff[ns][kk]];
      #pragma unroll
      for (int ms=0; ms<4; ms++)
        #pragma unroll
        for (int ns=0; ns<4; ns++)
          acc[ms][ns] = __builtin_amdgcn_mfma_f32_16x16x32_bf16(af[ms], bfr[ns], acc[ms][ns], 0,0,0);
    }
    __syncthreads();
  }
  u16* pbase = part + (size_t)blockIdx.z*M_*ldc;
  #pragma unroll
  for (int ms=0; ms<4; ms++){
    #pragma unroll
    for (int ns=0; ns<4; ns++){
      int c = col0 + 64*wx + 16*ns + ln;
      #pragma unroll
      for (int i=0;i<4;i++){
        int r = row0 + 64*wy + 16*ms + quad*4 + i;
        pbase[(size_t)r*ldc + c] = f2b(acc[ms][ns][i]);
      }
    }
  }
}

// ---------------- 4-slice reduce + bias + gate + residual -> f32 out
template<int GIDX>
__global__ __launch_bounds__(256) void k_red4(const u16* __restrict__ part,
    const float* __restrict__ Wb, const float* __restrict__ mod,
    const float* __restrict__ resid, float* __restrict__ outp)
{
  size_t i = ((size_t)blockIdx.x*256 + threadIdx.x)*4;
  int c = (int)(i & 1023); int r = (int)(i >> 10); int b = r >> 9;
  uint2 a0 = *(const uint2*)(part + i);
  uint2 a1 = *(const uint2*)(part + (size_t)M_*D_ + i);
  uint2 a2 = *(const uint2*)(part + (size_t)2*M_*D_ + i);
  uint2 a3 = *(const uint2*)(part + (size_t)3*M_*D_ + i);
  float4 pv;
  pv.x = b2f((u16)(a0.x&0xffff)) + b2f((u16)(a1.x&0xffff)) + b2f((u16)(a2.x&0xffff)) + b2f((u16)(a3.x&0xffff));
  pv.y = b2f((u16)(a0.x>>16))    + b2f((u16)(a1.x>>16))    + b2f((u16)(a2.x>>16))    + b2f((u16)(a3.x>>16));
  pv.z = b2f((u16)(a0.y&0xffff)) + b2f((u16)(a1.y&0xffff)) + b2f((u16)(a2.y&0xffff)) + b2f((u16)(a3.y&0xffff));
  pv.w = b2f((u16)(a0.y>>16))    + b2f((u16)(a1.y>>16))    + b2f((u16)(a2.y>>16))    + b2f((u16)(a3.y>>16));
  float4 x4 = *(const float4*)(resid + i);
  float4 bi = *(const float4*)(Wb + c);
  float4 g4 = *(const float4*)(mod + b*6*D_ + GIDX*D_ + c);
  float4 o;
  o.x = x4.x + g4.x*(pv.x + bi.x);
  o.y = x4.y + g4.y*(pv.y + bi.y);
  o.z = x4.z + g4.z*(pv.z + bi.z);
  o.w = x4.w + g4.w*(pv.w + bi.w);
  *(float4*)(outp + i) = o;
}

// ---------------- PROJ (bias already in GEMM epilogue) + gate_s + residual
// -> xm, LN2+mod -> xn.
__global__ __launch_bounds__(256) void k_redln(const u16* __restrict__ proj,
    const float* __restrict__ mod, const float* __restrict__ resid,
    const float* __restrict__ g, const float* __restrict__ be,
    float* __restrict__ xm, u16* __restrict__ xn)
{
  int row = blockIdx.x, b = row >> 9, tid = threadIdx.x;
  size_t i = (size_t)row*D_ + tid*4;
  int c = tid*4;
  uint2 a0 = *(const uint2*)(proj + i);
  float4 pv;
  pv.x = b2f((u16)(a0.x&0xffff));
  pv.y = b2f((u16)(a0.x>>16));
  pv.z = b2f((u16)(a0.y&0xffff));
  pv.w = b2f((u16)(a0.y>>16));
  float4 x4 = *(const float4*)(resid + i);
  float4 g4 = *(const float4*)(mod + b*6*D_ + 2*D_ + c);
  float4 mid;
  mid.x = x4.x + g4.x*pv.x;
  mid.y = x4.y + g4.y*pv.y;
  mid.z = x4.z + g4.z*pv.z;
  mid.w = x4.w + g4.w*pv.w;
  *(float4*)(xm + i) = mid;
  float s = mid.x+mid.y+mid.z+mid.w;
  float s2 = mid.x*mid.x+mid.y*mid.y+mid.z*mid.z+mid.w*mid.w;
  #pragma unroll
  for (int o=32;o>0;o>>=1){ s += __shfl_down(s,o); s2 += __shfl_down(s2,o); }
  __shared__ float rs[4], rs2[4];
  int w = tid >> 6;
  if ((tid & 63)==0){ rs[w]=s; rs2[w]=s2; }
  __syncthreads();
  s = rs[0]+rs[1]+rs[2]+rs[3]; s2 = rs2[0]+rs2[1]+rs2[2]+rs2[3];
  float mu = s * (1.f/D_);
  float var = s2 * (1.f/D_) - mu*mu;
  float rstd = rsqrtf(var + 1e-5f);
  const float* mrow = mod + b*6*D_;
  float4 gg = *(const float4*)(g + c);
  float4 bb = *(const float4*)(be + c);
  float4 sc = *(const float4*)(mrow + 4*D_ + c);
  float4 sh = *(const float4*)(mrow + 3*D_ + c);
  u16 o[4];
  o[0] = f2b(((mid.x-mu)*rstd*gg.x + bb.x)*(1.f+sc.x) + sh.x);
  o[1] = f2b(((mid.y-mu)*rstd*gg.y + bb.y)*(1.f+sc.y) + sh.y);
  o[2] = f2b(((mid.z-mu)*rstd*gg.z + bb.z)*(1.f+sc.z) + sh.z);
  o[3] = f2b(((mid.w-mu)*rstd*gg.w + bb.w)*(1.f+sc.w) + sh.w);
  *(uint2*)(xn + i) = *(const uint2*)o;
}

// ---------------- flash attention: block = (nt64, h, b), 4 waves, 64 q-rows
// Bias tile staged in LDS (coalesced uint4) inside the K/V staging block.
__global__ __launch_bounds__(256) void k_attn(const u16* __restrict__ qkv,
    const u16* __restrict__ biasbuf, u16* __restrict__ attn_out)
{
  __shared__ __align__(16) u16 Qs[64*72];
  __shared__ __align__(16) u16 Ks[64*72];
  __shared__ __align__(16) u16 Vt[64*72];
  __shared__ __align__(16) u16 Bt[64*72];
  __shared__ __align__(16) u16 Ps[4*16*72];
  int nt = blockIdx.x, h = blockIdx.y, b = blockIdx.z;
  int n0 = nt*64;
  int tid = threadIdx.x;
  int w = tid >> 6, lane = tid & 63, ln = lane & 15, quad = lane >> 4;

  {
    int row = tid >> 2, cb = (tid & 3)*16;
    const u16* src = qkv + (size_t)(b*N_ + n0 + row)*3072 + h*64 + cb;
    uint4 q0 = *(const uint4*)src, q1 = *(const uint4*)(src+8);
    uint4* dst = (uint4*)&Qs[row*72 + cb];
    dst[0] = q0; dst[1] = q1;
  }
  __syncthreads();
  bf16x8 qf[2];
  qf[0] = *(const bf16x8*)&Qs[(16*w+ln)*72 + quad*8];
  qf[1] = *(const bf16x8*)&Qs[(16*w+ln)*72 + 32 + quad*8];

  f32x4 oacc[4] = {};
  float rmax[4] = {-3e38f,-3e38f,-3e38f,-3e38f};
  float rsum[4] = {0.f,0.f,0.f,0.f};
  const u16* bbase = biasbuf + (((size_t)(b*H_ + h)*N_) + n0)*N_;

  for (int mt = 0; mt < 8; mt++){
    __syncthreads();
    {
      int r = tid >> 2, cb = (tid & 3)*16;
      const u16* kp = qkv + (size_t)(b*N_ + mt*64 + r)*3072 + 1024 + h*64 + cb;
      uint4 k0 = *(const uint4*)kp, k1 = *(const uint4*)(kp+8);
      uint4* kd = (uint4*)&Ks[r*72 + cb];
      kd[0] = k0; kd[1] = k1;
      const u16* vp = qkv + (size_t)(b*N_ + mt*64 + r)*3072 + 2048 + h*64 + cb;
      uint4 v0 = *(const uint4*)vp, v1 = *(const uint4*)(vp+8);
      u16 ve[16];
      *(uint4*)&ve[0] = v0; *(uint4*)&ve[8] = v1;
      #pragma unroll
      for (int j=0;j<16;j++) Vt[(cb+j)*72 + r] = ve[j];
      // bias tile [64 q-rows][64 m-cols], coalesced 2x uint4 per thread
      const u16* bsrc = bbase + (size_t)r*N_ + mt*64 + cb;
      uint4 b0 = *(const uint4*)bsrc, b1 = *(const uint4*)(bsrc+8);
      uint4* bd = (uint4*)&Bt[r*72 + cb];
      bd[0] = b0; bd[1] = b1;
    }
    __syncthreads();

    f32x4 s[4];
    #pragma unroll
    for (int cs=0; cs<4; cs++){
      bf16x8 k0f = *(const bf16x8*)&Ks[(16*cs+ln)*72 + quad*8];
      bf16x8 k1f = *(const bf16x8*)&Ks[(16*cs+ln)*72 + 32 + quad*8];
      f32x4 z = {};
      z = __builtin_amdgcn_mfma_f32_16x16x32_bf16(qf[0], k0f, z, 0,0,0);
      z = __builtin_amdgcn_mfma_f32_16x16x32_bf16(qf[1], k1f, z, 0,0,0);
      s[cs] = z;
    }
    #pragma unroll
    for (int cs=0; cs<4; cs++)
      #pragma unroll
      for (int i=0;i<4;i++)
        s[cs][i] = s[cs][i]*0.125f + b2f(Bt[(16*w + quad*4 + i)*72 + 16*cs + ln]);

    #pragma unroll
    for (int i=0;i<4;i++){
      float tm = fmaxf(fmaxf(s[0][i], s[1][i]), fmaxf(s[2][i], s[3][i]));
      #pragma unroll
      for (int o=1;o<16;o<<=1) tm = fmaxf(tm, __shfl_xor(tm, o));
      float nm = fmaxf(rmax[i], tm);
      float alpha = __expf(rmax[i] - nm);
      rmax[i] = nm;
      float ps = 0.f;
      #pragma unroll
      for (int cs=0; cs<4; cs++){
        float p = __expf(s[cs][i] - nm);
        s[cs][i] = p; ps += p;
      }
      #pragma unroll
      for (int o=1;o<16;o<<=1) ps += __shfl_xor(ps, o);
      rsum[i] = rsum[i]*alpha + ps;
      #pragma unroll
      for (int ds=0; ds<4; ds++) oacc[ds][i] *= alpha;
    }

    #pragma unroll
    for (int cs=0; cs<4; cs++)
      #pragma unroll
      for (int i=0;i<4;i++)
        Ps[w*1152 + (quad*4+i)*72 + 16*cs + ln] = f2b(s[cs][i]);

    bf16x8 pf0 = *(const bf16x8*)&Ps[w*1152 + ln*72 + quad*8];
    bf16x8 pf1 = *(const bf16x8*)&Ps[w*1152 + ln*72 + 32 + quad*8];
    #pragma unroll
    for (int ds=0; ds<4; ds++){
      bf16x8 v0f = *(const bf16x8*)&Vt[(16*ds+ln)*72 + quad*8];
      bf16x8 v1f = *(const bf16x8*)&Vt[(16*ds+ln)*72 + 32 + quad*8];
      oacc[ds] = __builtin_amdgcn_mfma_f32_16x16x32_bf16(pf0, v0f, oacc[ds], 0,0,0);
      oacc[ds] = __builtin_amdgcn_mfma_f32_16x16x32_bf16(pf1, v1f, oacc[ds], 0,0,0);
    }
  }

  #pragma unroll
  for (int i=0;i<4;i++){
    float inv = 1.f / rsum[i];
    int r = b*N_ + n0 + 16*w + quad*4 + i;
    #pragma unroll
    for (int ds=0; ds<4; ds++)
      attn_out[(size_t)r*D_ + h*64 + 16*ds + ln] = f2b(oacc[ds][i]*inv);
  }
}

extern "C" void kernel_launch(void* const* d_in, const int* in_sizes, int n_in,
                              void* d_out, int out_size, void* d_ws, size_t ws_size,
                              hipStream_t stream) {
  const float* x      = (const float*)d_in[0];
  const float* t_emb  = (const float*)d_in[1];
  const float* rel    = (const float*)d_in[2];
  const int*   amask  = (const int*)d_in[3];
  const float* w_ada  = (const float*)d_in[4];
  const float* b_ada  = (const float*)d_in[5];
  const float* g1     = (const float*)d_in[6];
  const float* beta1  = (const float*)d_in[7];
  const float* g2     = (const float*)d_in[8];
  const float* beta2  = (const float*)d_in[9];
  const float* w_qkv  = (const float*)d_in[10];
  const float* b_qkv  = (const float*)d_in[11];
  const float* w_proj = (const float*)d_in[12];
  const float* b_proj = (const float*)d_in[13];
  const float* w_rp1  = (const float*)d_in[14];
  const float* b_rp1  = (const float*)d_in[15];
  const float* w_rp2  = (const float*)d_in[16];
  const float* b_rp2  = (const float*)d_in[17];
  const float* w_fc1  = (const float*)d_in[18];
  const float* b_fc1  = (const float*)d_in[19];
  const float* w_fc2  = (const float*)d_in[20];
  const float* b_fc2  = (const float*)d_in[21];
  float* outp = (float*)d_out;

  const size_t MB = 1u<<20;
  char* wsb = (char*)d_ws;
  float* mod   = (float*)(wsb);
  u16*  xn     = (u16*) (wsb + 131072);
  float* xm    = (float*)(wsb + 131072 + 4*MB);
  u16*  wqkvb  = (u16*) (wsb + 131072 + 12*MB);
  u16*  wprojb = (u16*) (wsb + 131072 + 18*MB);
  u16*  wfc1b  = (u16*) (wsb + 131072 + 20*MB);
  u16*  wfc2b  = (u16*) (wsb + 131072 + 28*MB);
  u16*  qkvb   = (u16*) (wsb + 131072 + 36*MB);
  u16*  biasb  = (u16*) (wsb + 131072 + 48*MB);
  u16*  hb     = (u16*) (wsb + 131072 + 80*MB);
  u16*  parts  = (u16*) (wsb + 131072 + 96*MB);   // also projb (4.2MB)

  // 1) merged pre-pass: converts + adaLN mod + rel-pos bias (one launch)
  k_pre<<<5632, 256, 0, stream>>>(
      w_qkv, wqkvb, w_proj, wprojb, w_fc1, wfc1b, w_fc2, wfc2b,
      t_emb, w_ada, b_ada, mod,
      rel, amask, w_rp1, b_rp1, w_rp2, b_rp2, biasb);
  // 2) LN1
  k_lnmod<<<M_, 256, 0, stream>>>(x, g1, beta1, mod, 0, 1, xn);
  // 3) QKV 64x128 direct (768 blk = 3/CU balanced, XCD-swizzled)
  k_gemm64<EPI_PLAIN><<<dim3(3072/128, M_/64), 256, 0, stream>>>(
      xn, wqkvb, b_qkv, D_, 3072, qkvb);
  // 4) attention (bias tile LDS-staged)
  k_attn<<<dim3(8, H_, B_), 256, 0, stream>>>(qkvb, biasb, xn);
  // 5) PROJ 64x128 direct, bias fused (256 blk = 1/CU, XCD-swizzled)
  k_gemm64<EPI_PLAIN><<<dim3(D_/128, M_/64), 256, 0, stream>>>(
      xn, wprojb, b_proj, D_, D_, parts);
  // 6) PROJ gate+residual -> xm, LN2 -> xn
  k_redln<<<M_, 256, 0, stream>>>(parts, mod, x, g2, beta2, xm, xn);
  // 7) FC1 64x128 + GELU (1024 blk = 4/CU, XCD-swizzled)
  k_gemm64<EPI_GELU><<<dim3(HID_/128, M_/64), 256, 0, stream>>>(
      xn, wfc1b, b_fc1, D_, HID_, hb);
  // 8) FC2 split-K x4 (512 blk = 2/CU, XCD-swizzled per z)
  k_gemm<<<dim3(D_/128, M_/128, 4), 256, 0, stream>>>(
      hb, wfc2b, HID_, HID_/4, D_, parts);
  // 9) FC2 reduce -> out
  k_red4<5><<<2048, 256, 0, stream>>>(parts, b_fc2, mod, xm, outp);
}